// Round 1
// baseline (50.133 us; speedup 1.0000x reference)
//
#include <hip/hip_runtime.h>
#include <hip/hip_bf16.h>
#include <stdint.h>

typedef float f32x4 __attribute__((ext_vector_type(4)));
typedef short s16x8 __attribute__((ext_vector_type(8)));
typedef unsigned short u16x4 __attribute__((ext_vector_type(4)));

#define LOG2E 1.4426950408889634f

__device__ inline unsigned short f2bf(float f){
    __hip_bfloat16 h = __float2bfloat16(f);
    return __builtin_bit_cast(unsigned short, h);
}
__device__ inline float bf2f(unsigned short u){
    unsigned v = ((unsigned)u) << 16;
    return __builtin_bit_cast(float, v);
}
__device__ inline float exp2_fast(float x){
#if __has_builtin(__builtin_amdgcn_exp2f)
    return __builtin_amdgcn_exp2f(x);
#else
    float r; asm volatile("v_exp_f32 %0, %1\n\ts_nop 0\n\ts_nop 0" : "=v"(r) : "v"(x)); return r;
#endif
}
__device__ inline void gld_lds16(const void* g, void* l){
    __builtin_amdgcn_global_load_lds((const __attribute__((address_space(1))) unsigned*)g,
                                     (__attribute__((address_space(3))) unsigned*)l, 16, 0, 0);
}

// ---------------- K0: Wt[c][k] = bf16(W[k][c])  (256x256) ----------------
__global__ __launch_bounds__(256) void k_wt(const float* __restrict__ W,
                                            unsigned short* __restrict__ Wt){
    int c = blockIdx.x, k = threadIdx.x;
    Wt[c*256 + k] = f2bf(W[k*256 + c]);   // write coalesced; reads absorbed by L2 (W=256KB)
}

// ---------------- K1: hT[b][h][d][n] = bf16( (x @ W)[b*1024+n][h*64+d] ) ----------------
// grid 512 (128 row-blocks x 4 col-blocks==heads), 4 waves, 16x16x32 bf16 MFMA
__global__ __launch_bounds__(256) void k_gemm(const float* __restrict__ x,
                                              const unsigned short* __restrict__ Wt,
                                              unsigned short* __restrict__ hT){
    __shared__ unsigned short trans[64][68];   // +4 pad: conflict-light b64 column reads
    int orig = blockIdx.x;
    int swz  = (orig & 7)*64 + (orig >> 3);    // XCD-chunked: keeps the 4 col-blocks of a row-block on one XCD
    int rbi = swz >> 2, cbi = swz & 3;
    int tid = threadIdx.x;
    int w = tid >> 6, lane = tid & 63;
    int r16 = lane & 15, kq = lane >> 4;

    const float*          xp = x  + (size_t)((rbi*64 + w*16 + r16)*256 + kq*8);
    const unsigned short* wp = Wt + (size_t)((cbi*64 + r16)*256 + kq*8);

    f32x4 acc[4] = {{0,0,0,0},{0,0,0,0},{0,0,0,0},{0,0,0,0}};
    #pragma unroll
    for (int ks=0; ks<8; ++ks){
        f32x4 xa = *(const f32x4*)(xp + ks*32);
        f32x4 xb = *(const f32x4*)(xp + ks*32 + 4);
        s16x8 af;
        af[0]=(short)f2bf(xa[0]); af[1]=(short)f2bf(xa[1]);
        af[2]=(short)f2bf(xa[2]); af[3]=(short)f2bf(xa[3]);
        af[4]=(short)f2bf(xb[0]); af[5]=(short)f2bf(xb[1]);
        af[6]=(short)f2bf(xb[2]); af[7]=(short)f2bf(xb[3]);
        #pragma unroll
        for (int t=0;t<4;++t){
            s16x8 bf = *(const s16x8*)(wp + t*16*256 + ks*32);   // Wt L2-resident
            acc[t] = __builtin_amdgcn_mfma_f32_16x16x32_bf16(af, bf, acc[t], 0,0,0);
        }
    }
    // C/D frag: col = lane&15, row = (lane>>4)*4 + j   [measured m89]
    #pragma unroll
    for (int t=0;t<4;++t)
        #pragma unroll
        for (int j=0;j<4;++j)
            trans[t*16 + r16][w*16 + kq*4 + j] = f2bf(acc[t][j]);
    __syncthreads();
    int d = tid & 63, seg = tid >> 6;
    int b  = rbi >> 4;
    int n0 = (rbi & 15) * 64;
    unsigned short* dst = hT + ((size_t)((b*4 + cbi)*64 + d))*1024 + n0 + seg*16;
    #pragma unroll
    for (int q=0;q<4;++q){
        u16x4 v = *(const u16x4*)&trans[d][seg*16 + q*4];
        *(u16x4*)(dst + q*4) = v;
    }
}

// ---------------- K2: e_i, e_j, maxj per (b,h) ----------------
__global__ __launch_bounds__(256) void k_ev(const unsigned short* __restrict__ hT,
                                            const float* __restrict__ a,
                                            float* __restrict__ ei, float* __restrict__ ej,
                                            float* __restrict__ mj){
    int bh = blockIdx.x;
    int h  = bh & 3;
    int tid = threadIdx.x;
    const unsigned short* base = hT + (size_t)bh*64*1024 + tid*4;
    float acc1[4] = {0,0,0,0}, acc2[4] = {0,0,0,0};
    for (int d=0; d<64; ++d){
        float va1 = a[h*128 + d];
        float va2 = a[h*128 + 64 + d];
        u16x4 v = *(const u16x4*)(base + (size_t)d*1024);
        #pragma unroll
        for (int i=0;i<4;++i){
            float f = bf2f(v[i]);
            acc1[i] = __builtin_fmaf(f, va1, acc1[i]);
            acc2[i] = __builtin_fmaf(f, va2, acc2[i]);
        }
    }
    #pragma unroll
    for (int i=0;i<4;++i){
        ei[bh*1024 + tid*4 + i] = acc1[i];
        ej[bh*1024 + tid*4 + i] = acc2[i];
    }
    float lmax = fmaxf(fmaxf(acc2[0],acc2[1]), fmaxf(acc2[2],acc2[3]));
    #pragma unroll
    for (int off=32; off; off>>=1) lmax = fmaxf(lmax, __shfl_xor(lmax, off));
    __shared__ float red[4];
    if ((tid & 63)==0) red[tid>>6] = lmax;
    __syncthreads();
    if (tid==0) mj[bh] = fmaxf(fmaxf(red[0],red[1]), fmaxf(red[2],red[3]));
}

// ---------------- K3: fused mask + softmax + PV ----------------
// block = 4 waves, 64 q-rows (wave w owns rows qb+w*16 .. +15); K-slab = 64 m, double-buffered
__global__ __launch_bounds__(256) void k_attn(const float* __restrict__ adj,
                                              const unsigned short* __restrict__ hT,
                                              const float* __restrict__ ei,
                                              const float* __restrict__ ejg,
                                              const float* __restrict__ mj,
                                              float* __restrict__ out){
    __shared__ alignas(16) unsigned short slab[2][64*64];   // [d][m] 2x8KB, chunk-XOR-swizzled
    __shared__ alignas(16) float ejs[1024];
    int orig = blockIdx.x;
    int swz  = (orig & 7)*64 + (orig >> 3);   // XCD-chunked: 4 hT panels (512KB) per XCD L2
    int bh = swz >> 4, qi = swz & 15;
    int b = bh >> 2, h = bh & 3;
    int tid = threadIdx.x, w = tid >> 6, lane = tid & 63;
    int r16 = lane & 15, kq = lane >> 4;
    int qb = qi*64;
    int nrow = qb + w*16 + r16;                // this lane's A-row (score row)

    *(f32x4*)(ejs + tid*4) = *(const f32x4*)(ejg + bh*1024 + tid*4);

    float eir = ei[bh*1024 + nrow];
    float s0  = eir + mj[bh];
    float stab2 = fmaxf(s0, 0.2f*s0) * LOG2E;  // row-max upper bound (lrelu monotone), exp2 arg <= ~0

    const unsigned short* hTb  = hT + (size_t)bh*64*1024;
    const float* adjrow        = adj + ((size_t)(b*1024 + nrow))*1024;

    f32x4 acc[4] = {{0,0,0,0},{0,0,0,0},{0,0,0,0},{0,0,0,0}};
    float rs = 0.f;

    auto stage = [&](int buf, int ms){
        int m0 = ms*64;
        #pragma unroll
        for (int c=0;c<2;++c){
            int dd = c*32 + (tid >> 3);
            int ck = (tid & 7) ^ (dd & 7);                       // pre-swizzled global source
            const unsigned short* src = hTb + (size_t)dd*1024 + m0 + ck*8;
            char* ldst = (char*)&slab[buf][0] + c*4096 + w*1024; // wave-uniform dest, linear
            gld_lds16(src, ldst);
        }
    };

    stage(0, 0);
    __syncthreads();
    for (int ms=0; ms<16; ++ms){
        int cur = ms & 1;
        if (ms < 15) stage(cur^1, ms+1);      // prefetch next slab; latency hidden under compute
        int m0 = ms*64;
        #pragma unroll
        for (int kb=0; kb<2; ++kb){
            const float* ap = adjrow + m0 + kb*32 + kq*8;
            f32x4 ad0 = *(const f32x4*)ap;
            f32x4 ad1 = *(const f32x4*)(ap + 4);
            const float* ejp = ejs + m0 + kb*32 + kq*8;
            f32x4 ej0 = *(const f32x4*)ejp;    // broadcast within kq group: conflict-free
            f32x4 ej1 = *(const f32x4*)(ejp + 4);
            s16x8 pf;
            float pv[8];
            #pragma unroll
            for (int j=0;j<8;++j){
                float ejv = (j<4) ? ej0[j] : ej1[j-4];
                float av  = (j<4) ? ad0[j] : ad1[j-4];
                float s  = eir + ejv;
                float t2 = fmaxf(s, 0.2f*s);                       // leaky-relu
                float e  = exp2_fast(__builtin_fmaf(t2, LOG2E, -stab2));
                unsigned short pb = f2bf(av * e);                  // adj in {0,1}: mask == multiply
                pf[j] = (short)pb;
                pv[j] = bf2f(pb);                                  // denominator from the SAME bf16 weights
            }
            rs += ((pv[0]+pv[1])+(pv[2]+pv[3])) + ((pv[4]+pv[5])+(pv[6]+pv[7]));
            #pragma unroll
            for (int t=0;t<4;++t){
                int dd = t*16 + r16;
                int co = (kb*4 + kq) ^ (dd & 7);                   // un-swizzle on read
                s16x8 bf = *(const s16x8*)(&slab[cur][0] + dd*64 + co*8);
                acc[t] = __builtin_amdgcn_mfma_f32_16x16x32_bf16(pf, bf, acc[t], 0,0,0);
            }
        }
        __syncthreads();   // drains vmcnt: next slab staged & this slab's readers done
    }

    // rowsum: lanes {r,r+16,r+32,r+48} hold partials of row r
    rs += __shfl_xor(rs, 16);
    rs += __shfl_xor(rs, 32);
    #pragma unroll
    for (int j=0;j<4;++j){
        float rsj = __shfl(rs, kq*4 + j);      // lane kq*4+j holds rowsum of row kq*4+j
        float inv = 1.0f / rsj;
        int n = qb + w*16 + kq*4 + j;
        float* op = out + ((size_t)(b*1024 + n))*256 + h*64 + r16;
        #pragma unroll
        for (int t=0;t<4;++t)
            op[t*16] = acc[t][j] * inv;
    }
}

extern "C" void kernel_launch(void* const* d_in, const int* in_sizes, int n_in,
                              void* d_out, int out_size, void* d_ws, size_t ws_size,
                              hipStream_t stream){
    const float* x   = (const float*)d_in[0];
    const float* adj = (const float*)d_in[1];
    const float* W   = (const float*)d_in[2];
    const float* a   = (const float*)d_in[3];
    float* out = (float*)d_out;
    char* ws = (char*)d_ws;
    // ws layout: Wt 128KB | hT 4MB | e_i 128KB | e_j 128KB | maxj 128B  (~4.6MB total)
    unsigned short* Wt = (unsigned short*)ws;
    unsigned short* hT = (unsigned short*)(ws + (128<<10));
    float* ei = (float*)(ws + (128<<10) + (4<<20));
    float* ej = ei + 32768;
    float* mj = ej + 32768;

    k_wt  <<<256, 256, 0, stream>>>(W, Wt);
    k_gemm<<<512, 256, 0, stream>>>(x, Wt, hT);
    k_ev  <<<32,  256, 0, stream>>>(hT, a, ei, ej, mj);
    k_attn<<<512, 256, 0, stream>>>(adj, hT, ei, ej, mj, out);
}

// Round 2
// 49.613 us; speedup vs baseline: 1.0105x; 1.0105x over previous
//
#include <hip/hip_runtime.h>
#include <hip/hip_bf16.h>
#include <stdint.h>

typedef float f32x4 __attribute__((ext_vector_type(4)));
typedef short s16x8 __attribute__((ext_vector_type(8)));
typedef unsigned short u16x4 __attribute__((ext_vector_type(4)));

#define LOG2E 1.4426950408889634f

__device__ inline unsigned short f2bf(float f){
    __hip_bfloat16 h = __float2bfloat16(f);
    return __builtin_bit_cast(unsigned short, h);
}
__device__ inline float bf2f(unsigned short u){
    unsigned v = ((unsigned)u) << 16;
    return __builtin_bit_cast(float, v);
}
__device__ inline float exp2_fast(float x){
#if __has_builtin(__builtin_amdgcn_exp2f)
    return __builtin_amdgcn_exp2f(x);
#else
    float r; asm volatile("v_exp_f32 %0, %1\n\ts_nop 0\n\ts_nop 0" : "=v"(r) : "v"(x)); return r;
#endif
}
__device__ inline void gld_lds16(const void* g, void* l){
    __builtin_amdgcn_global_load_lds((const __attribute__((address_space(1))) unsigned*)g,
                                     (__attribute__((address_space(3))) unsigned*)l, 16, 0, 0);
}

// ---------------- K0: Wt[c][k] = bf16(W[k][c])  (256x256) ----------------
__global__ __launch_bounds__(256) void k_wt(const float* __restrict__ W,
                                            unsigned short* __restrict__ Wt){
    int c = blockIdx.x, k = threadIdx.x;
    Wt[c*256 + k] = f2bf(W[k*256 + c]);
}

// ---------------- K0b: adj (fp32 {0,1}) -> bitmask, [b][n][16 x u64(m-slab)] ----------------
// one wave per row; 16 ballots; lane j<16 keeps mask_j -> one coalesced 128B row write
__global__ __launch_bounds__(256) void k_adjbits(const float* __restrict__ adj,
                                                 unsigned long long* __restrict__ abits){
    int w = threadIdx.x >> 6, lane = threadIdx.x & 63;
    int row = blockIdx.x*4 + w;                       // b*1024 + n, 0..8191
    const float* src = adj + (size_t)row*1024 + lane;
    unsigned long long my = 0;
    #pragma unroll
    for (int ms=0; ms<16; ++ms){
        float v = src[ms*64];                          // 256B coalesced per wave
        unsigned long long m = __ballot(v != 0.0f);    // bit lane = m-offset lane
        if (lane == ms) my = m;
    }
    if (lane < 16) abits[(size_t)row*16 + lane] = my;
}

// ---------------- K1: hT[b][h][d][n] = bf16(x@W), + e_i/e_j epilogue (prescaled by LOG2E) ----
__global__ __launch_bounds__(256) void k_gemm(const float* __restrict__ x,
                                              const unsigned short* __restrict__ Wt,
                                              const float* __restrict__ a,
                                              unsigned short* __restrict__ hT,
                                              float* __restrict__ eiL,
                                              float* __restrict__ ejL){
    __shared__ unsigned short trans[64][68];
    __shared__ float red[2][4][64];
    int orig = blockIdx.x;
    int swz  = (orig & 7)*64 + (orig >> 3);    // 4 col-blocks of a row-block on one XCD (x reuse)
    int rbi = swz >> 2, cbi = swz & 3;
    int tid = threadIdx.x;
    int w = tid >> 6, lane = tid & 63;
    int r16 = lane & 15, kq = lane >> 4;

    const float*          xp = x  + (size_t)((rbi*64 + w*16 + r16)*256 + kq*8);
    const unsigned short* wp = Wt + (size_t)((cbi*64 + r16)*256 + kq*8);

    f32x4 acc[4] = {{0,0,0,0},{0,0,0,0},{0,0,0,0},{0,0,0,0}};
    #pragma unroll
    for (int ks=0; ks<8; ++ks){
        f32x4 xa = *(const f32x4*)(xp + ks*32);
        f32x4 xb = *(const f32x4*)(xp + ks*32 + 4);
        s16x8 af;
        af[0]=(short)f2bf(xa[0]); af[1]=(short)f2bf(xa[1]);
        af[2]=(short)f2bf(xa[2]); af[3]=(short)f2bf(xa[3]);
        af[4]=(short)f2bf(xb[0]); af[5]=(short)f2bf(xb[1]);
        af[6]=(short)f2bf(xb[2]); af[7]=(short)f2bf(xb[3]);
        #pragma unroll
        for (int t=0;t<4;++t){
            s16x8 bf = *(const s16x8*)(wp + t*16*256 + ks*32);
            acc[t] = __builtin_amdgcn_mfma_f32_16x16x32_bf16(af, bf, acc[t], 0,0,0);
        }
    }
    #pragma unroll
    for (int t=0;t<4;++t)
        #pragma unroll
        for (int j=0;j<4;++j)
            trans[t*16 + r16][w*16 + kq*4 + j] = f2bf(acc[t][j]);
    __syncthreads();

    int b  = rbi >> 4;
    int n0 = (rbi & 15) * 64;

    // hT write
    {
        int d = tid & 63, seg = tid >> 6;
        unsigned short* dst = hT + ((size_t)((b*4 + cbi)*64 + d))*1024 + n0 + seg*16;
        #pragma unroll
        for (int q=0;q<4;++q){
            u16x4 v = *(const u16x4*)&trans[d][seg*16 + q*4];
            *(u16x4*)(dst + q*4) = v;
        }
    }

    // e_i / e_j partials over this block's full d-range (64 = whole head)
    {
        int seg = tid >> 6, n = tid & 63;
        const float* ap = a + cbi*128;        // a1 = ap[0:64], a2 = ap[64:128] (wave-uniform loads)
        float p1 = 0.f, p2 = 0.f;
        #pragma unroll
        for (int q=0;q<16;++q){
            int dd = seg*16 + q;
            float hv = bf2f(trans[dd][n]);
            p1 = __builtin_fmaf(hv, ap[dd],    p1);
            p2 = __builtin_fmaf(hv, ap[64+dd], p2);
        }
        red[0][seg][n] = p1;
        red[1][seg][n] = p2;
    }
    __syncthreads();
    if (tid < 128){
        int which = tid >> 6, nn = tid & 63;
        float s = red[which][0][nn] + red[which][1][nn] + red[which][2][nn] + red[which][3][nn];
        float* dst = which ? ejL : eiL;
        dst[(size_t)(b*4 + cbi)*1024 + n0 + nn] = s * LOG2E;
    }
}

// ---------------- K3: fused mask + softmax + PV (bitmask adj, no stabilizer) ----------------
__global__ __launch_bounds__(256) void k_attn(const uint2* __restrict__ abits,
                                              const unsigned short* __restrict__ hT,
                                              const float* __restrict__ eiL,
                                              const float* __restrict__ ejLg,
                                              float* __restrict__ out){
    __shared__ alignas(16) unsigned short slab[2][64*64];   // [d][m], chunk-XOR-swizzled
    __shared__ alignas(16) float ejs[1024];
    int orig = blockIdx.x;
    int swz  = (orig & 7)*64 + (orig >> 3);   // XCD-chunked: hT panels L2-local
    int bh = swz >> 4, qi = swz & 15;
    int b = bh >> 2;
    int tid = threadIdx.x, w = tid >> 6, lane = tid & 63;
    int r16 = lane & 15, kq = lane >> 4, kq8 = kq*8;
    int qb = qi*64;
    int nrow = qb + w*16 + r16;

    *(f32x4*)(ejs + tid*4) = *(const f32x4*)(ejLg + bh*1024 + tid*4);

    float eirL = eiL[bh*1024 + nrow];

    const unsigned short* hTb = hT + (size_t)bh*64*1024;
    const uint2* abrow        = abits + ((size_t)(b*1024 + nrow))*16;

    f32x4 acc[4] = {{0,0,0,0},{0,0,0,0},{0,0,0,0},{0,0,0,0}};
    float rs = 0.f;

    auto stage = [&](int buf, int ms){
        int m0 = ms*64;
        #pragma unroll
        for (int c=0;c<2;++c){
            int dd = c*32 + (tid >> 3);
            int ck = (tid & 7) ^ (dd & 7);                       // pre-swizzled global source
            const unsigned short* src = hTb + (size_t)dd*1024 + m0 + ck*8;
            char* ldst = (char*)&slab[buf][0] + c*4096 + w*1024; // linear wave-uniform dest
            gld_lds16(src, ldst);
        }
    };

    uint2 abcur = abrow[0];
    stage(0, 0);
    __syncthreads();
    for (int ms=0; ms<16; ++ms){
        int cur = ms & 1;
        uint2 abnext = abcur;
        if (ms < 15){ stage(cur^1, ms+1); abnext = abrow[ms+1]; }   // prefetch next slab + next bits
        unsigned wlo = abcur.x >> kq8;     // this lane's 8 mask bits, kb=0
        unsigned whi = abcur.y >> kq8;     // kb=1
        #pragma unroll
        for (int kb=0; kb<2; ++kb){
            unsigned word = kb ? whi : wlo;
            const float* ejp = ejs + ms*64 + kb*32 + kq8;
            f32x4 ej0 = *(const f32x4*)ejp;           // broadcast within kq group
            f32x4 ej1 = *(const f32x4*)(ejp + 4);
            s16x8 pf;
            float pv[8];
            #pragma unroll
            for (int j=0;j<8;++j){
                float ejv = (j<4) ? ej0[j] : ej1[j-4];
                float sL = eirL + ejv;                 // already in log2 domain
                float t  = fmaxf(sL, 0.2f*sL);         // leaky-relu (monotone, scale-safe)
                float e  = exp2_fast(t);               // no stabilizer needed: t in [-3,~16]
                float bitf = (float)((word >> j) & 1u);
                unsigned short pb = f2bf(bitf * e);
                pf[j] = (short)pb;
                pv[j] = bf2f(pb);                      // denominator from the SAME bf16 weights
            }
            rs += ((pv[0]+pv[1])+(pv[2]+pv[3])) + ((pv[4]+pv[5])+(pv[6]+pv[7]));
            #pragma unroll
            for (int t=0;t<4;++t){
                int dd = t*16 + r16;
                int co = (kb*4 + kq) ^ (dd & 7);       // un-swizzle on read
                s16x8 bf = *(const s16x8*)(&slab[cur][0] + dd*64 + co*8);
                acc[t] = __builtin_amdgcn_mfma_f32_16x16x32_bf16(pf, bf, acc[t], 0,0,0);
            }
        }
        __syncthreads();
        abcur = abnext;
    }

    rs += __shfl_xor(rs, 16);
    rs += __shfl_xor(rs, 32);
    int h = bh & 3;
    #pragma unroll
    for (int j=0;j<4;++j){
        float rsj = __shfl(rs, kq*4 + j);
        float inv = 1.0f / fmaxf(rsj, 1e-30f);
        int n = qb + w*16 + kq*4 + j;
        float* op = out + ((size_t)(b*1024 + n))*256 + h*64 + r16;
        #pragma unroll
        for (int t=0;t<4;++t)
            op[t*16] = acc[t][j] * inv;
    }
}

extern "C" void kernel_launch(void* const* d_in, const int* in_sizes, int n_in,
                              void* d_out, int out_size, void* d_ws, size_t ws_size,
                              hipStream_t stream){
    const float* x   = (const float*)d_in[0];
    const float* adj = (const float*)d_in[1];
    const float* W   = (const float*)d_in[2];
    const float* a   = (const float*)d_in[3];
    float* out = (float*)d_out;
    char* ws = (char*)d_ws;
    // ws: Wt 128KB | hT 4MB | eiL 128KB | ejL 128KB | abits 1MB
    unsigned short* Wt = (unsigned short*)ws;
    unsigned short* hT = (unsigned short*)(ws + (128<<10));
    float* eiL = (float*)(ws + (128<<10) + (4<<20));
    float* ejL = eiL + 32768;
    unsigned long long* abits = (unsigned long long*)(ws + (128<<10) + (4<<20) + (256<<10));

    k_wt     <<<256,  256, 0, stream>>>(W, Wt);
    k_adjbits<<<2048, 256, 0, stream>>>(adj, abits);
    k_gemm   <<<512,  256, 0, stream>>>(x, Wt, a, hT, eiL, ejL);
    k_attn   <<<512,  256, 0, stream>>>((const uint2*)abits, hT, eiL, ejL, out);
}

// Round 3
// 43.777 us; speedup vs baseline: 1.1452x; 1.1333x over previous
//
#include <hip/hip_runtime.h>
#include <hip/hip_bf16.h>
#include <stdint.h>

typedef float f32x4 __attribute__((ext_vector_type(4)));
typedef short s16x8 __attribute__((ext_vector_type(8)));
typedef unsigned short u16x4 __attribute__((ext_vector_type(4)));

#define LOG2E 1.4426950408889634f

__device__ inline unsigned short f2bf(float f){
    __hip_bfloat16 h = __float2bfloat16(f);
    return __builtin_bit_cast(unsigned short, h);
}
__device__ inline float bf2f(unsigned short u){
    unsigned v = ((unsigned)u) << 16;
    return __builtin_bit_cast(float, v);
}
__device__ inline float exp2_fast(float x){
#if __has_builtin(__builtin_amdgcn_exp2f)
    return __builtin_amdgcn_exp2f(x);
#else
    float r; asm volatile("v_exp_f32 %0, %1\n\ts_nop 0\n\ts_nop 0" : "=v"(r) : "v"(x)); return r;
#endif
}
__device__ inline void gld_lds16(const void* g, void* l){
    __builtin_amdgcn_global_load_lds((const __attribute__((address_space(1))) unsigned*)g,
                                     (__attribute__((address_space(3))) unsigned*)l, 16, 0, 0);
}

// ---------------- K0: fused {adj->bitmask, W->Wt transpose+bf16} ----------------
// blocks [0,2048): one wave per adj row; 16 ballots -> 128B coalesced row write
// blocks [2048,2304): Wt[c][k] = bf16(W[k][c])
__global__ __launch_bounds__(256) void k_prep(const float* __restrict__ adj,
                                              unsigned long long* __restrict__ abits,
                                              const float* __restrict__ W,
                                              unsigned short* __restrict__ Wt){
    int bid = blockIdx.x;
    if (bid < 2048){
        int w = threadIdx.x >> 6, lane = threadIdx.x & 63;
        int row = bid*4 + w;                          // b*1024 + n, 0..8191
        const float* src = adj + (size_t)row*1024 + lane;
        unsigned long long my = 0;
        #pragma unroll
        for (int ms=0; ms<16; ++ms){
            float v = src[ms*64];                      // 256B coalesced per wave
            unsigned long long m = __ballot(v != 0.0f);
            if (lane == ms) my = m;
        }
        if (lane < 16) abits[(size_t)row*16 + lane] = my;
    } else {
        int c = bid - 2048, k = threadIdx.x;
        Wt[c*256 + k] = f2bf(W[k*256 + c]);           // write coalesced; W L2-resident
    }
}

// ---------------- K1: hT[b][h][d][n] = bf16(x@W), + e_i/e_j epilogue (prescaled by LOG2E) ----
__global__ __launch_bounds__(256) void k_gemm(const float* __restrict__ x,
                                              const unsigned short* __restrict__ Wt,
                                              const float* __restrict__ a,
                                              unsigned short* __restrict__ hT,
                                              float* __restrict__ eiL,
                                              float* __restrict__ ejL){
    __shared__ unsigned short trans[64][68];
    __shared__ float red[2][4][64];
    int orig = blockIdx.x;
    int swz  = (orig & 7)*64 + (orig >> 3);    // XCD-chunked: x slab reused by 4 col-blocks
    int rbi = swz >> 2, cbi = swz & 3;
    int tid = threadIdx.x;
    int w = tid >> 6, lane = tid & 63;
    int r16 = lane & 15, kq = lane >> 4;

    const float*          xp = x  + (size_t)((rbi*64 + w*16 + r16)*256 + kq*8);
    const unsigned short* wp = Wt + (size_t)((cbi*64 + r16)*256 + kq*8);

    f32x4 acc[4] = {{0,0,0,0},{0,0,0,0},{0,0,0,0},{0,0,0,0}};
    #pragma unroll
    for (int ks=0; ks<8; ++ks){
        f32x4 xa = *(const f32x4*)(xp + ks*32);
        f32x4 xb = *(const f32x4*)(xp + ks*32 + 4);
        s16x8 af;
        af[0]=(short)f2bf(xa[0]); af[1]=(short)f2bf(xa[1]);
        af[2]=(short)f2bf(xa[2]); af[3]=(short)f2bf(xa[3]);
        af[4]=(short)f2bf(xb[0]); af[5]=(short)f2bf(xb[1]);
        af[6]=(short)f2bf(xb[2]); af[7]=(short)f2bf(xb[3]);
        #pragma unroll
        for (int t=0;t<4;++t){
            s16x8 bf = *(const s16x8*)(wp + t*16*256 + ks*32);
            acc[t] = __builtin_amdgcn_mfma_f32_16x16x32_bf16(af, bf, acc[t], 0,0,0);
        }
    }
    #pragma unroll
    for (int t=0;t<4;++t)
        #pragma unroll
        for (int j=0;j<4;++j)
            trans[t*16 + r16][w*16 + kq*4 + j] = f2bf(acc[t][j]);
    __syncthreads();

    int b  = rbi >> 4;
    int n0 = (rbi & 15) * 64;

    {   // hT write
        int d = tid & 63, seg = tid >> 6;
        unsigned short* dst = hT + ((size_t)((b*4 + cbi)*64 + d))*1024 + n0 + seg*16;
        #pragma unroll
        for (int q=0;q<4;++q){
            u16x4 v = *(const u16x4*)&trans[d][seg*16 + q*4];
            *(u16x4*)(dst + q*4) = v;
        }
    }

    {   // e_i / e_j partials over this block's full d-range (64 = whole head)
        int seg = tid >> 6, n = tid & 63;
        const float* ap = a + cbi*128;        // a1 = ap[0:64], a2 = ap[64:128]
        float p1 = 0.f, p2 = 0.f;
        #pragma unroll
        for (int q=0;q<16;++q){
            int dd = seg*16 + q;
            float hv = bf2f(trans[dd][n]);
            p1 = __builtin_fmaf(hv, ap[dd],    p1);
            p2 = __builtin_fmaf(hv, ap[64+dd], p2);
        }
        red[0][seg][n] = p1;
        red[1][seg][n] = p2;
    }
    __syncthreads();
    if (tid < 128){
        int which = tid >> 6, nn = tid & 63;
        float s = red[which][0][nn] + red[which][1][nn] + red[which][2][nn] + red[which][3][nn];
        float* dst = which ? ejL : eiL;
        dst[(size_t)(b*4 + cbi)*1024 + n0 + nn] = s * LOG2E;
    }
}

// ---------------- K3: fused mask + softmax + PV (bitmask adj, no stabilizer) ----------------
__global__ __launch_bounds__(256) void k_attn(const uint2* __restrict__ abits,
                                              const unsigned short* __restrict__ hT,
                                              const float* __restrict__ eiL,
                                              const float* __restrict__ ejLg,
                                              float* __restrict__ out){
    __shared__ alignas(16) unsigned short slab[2][64*64];   // [d][m], chunk-XOR-swizzled
    __shared__ alignas(16) float ejs[1024];
    int orig = blockIdx.x;
    int swz  = (orig & 7)*64 + (orig >> 3);   // XCD-chunked: same-b hT panel stays L2-local
    int bh = swz >> 4, qi = swz & 15;
    int b = bh >> 2;
    int tid = threadIdx.x, w = tid >> 6, lane = tid & 63;
    int r16 = lane & 15, kq = lane >> 4, kq8 = kq*8;
    int qb = qi*64;
    int nrow = qb + w*16 + r16;

    *(f32x4*)(ejs + tid*4) = *(const f32x4*)(ejLg + bh*1024 + tid*4);

    float eirL = eiL[bh*1024 + nrow];

    const unsigned short* hTb = hT + (size_t)bh*64*1024;
    const uint2* abrow        = abits + ((size_t)(b*1024 + nrow))*16;

    f32x4 acc[4] = {{0,0,0,0},{0,0,0,0},{0,0,0,0},{0,0,0,0}};
    float rs = 0.f;

    auto stage = [&](int buf, int ms){
        int m0 = ms*64;
        #pragma unroll
        for (int c=0;c<2;++c){
            int dd = c*32 + (tid >> 3);
            int ck = (tid & 7) ^ (dd & 7);                       // pre-swizzled global source
            const unsigned short* src = hTb + (size_t)dd*1024 + m0 + ck*8;
            char* ldst = (char*)&slab[buf][0] + c*4096 + w*1024; // linear wave-uniform dest
            gld_lds16(src, ldst);
        }
    };

    uint2 abcur = abrow[0];
    stage(0, 0);
    __syncthreads();
    for (int ms=0; ms<16; ++ms){
        int cur = ms & 1;
        uint2 abnext = abcur;
        if (ms < 15){ stage(cur^1, ms+1); abnext = abrow[ms+1]; }   // prefetch next slab + bits
        unsigned wlo = abcur.x >> kq8;
        unsigned whi = abcur.y >> kq8;
        #pragma unroll
        for (int kb=0; kb<2; ++kb){
            unsigned word = kb ? whi : wlo;
            const float* ejp = ejs + ms*64 + kb*32 + kq8;
            f32x4 ej0 = *(const f32x4*)ejp;           // broadcast within kq group
            f32x4 ej1 = *(const f32x4*)(ejp + 4);
            s16x8 pf;
            float pv[8];
            #pragma unroll
            for (int j=0;j<8;++j){
                float ejv = (j<4) ? ej0[j] : ej1[j-4];
                float sL = eirL + ejv;                 // log2 domain
                float t  = fmaxf(sL, 0.2f*sL);         // leaky-relu
                float e  = exp2_fast(t);               // t in [-3,~16]: no stabilizer needed
                float bitf = (float)((word >> j) & 1u);
                float pe = bitf * e;                   // adj in {0,1}: mask == multiply
                pf[j] = (short)f2bf(pe);
                pv[j] = pe;                            // denominator in f32 (pre-round)
            }
            rs += ((pv[0]+pv[1])+(pv[2]+pv[3])) + ((pv[4]+pv[5])+(pv[6]+pv[7]));
            #pragma unroll
            for (int t=0;t<4;++t){
                int dd = t*16 + r16;
                int co = (kb*4 + kq) ^ (dd & 7);       // un-swizzle on read
                s16x8 bf = *(const s16x8*)(&slab[cur][0] + dd*64 + co*8);
                acc[t] = __builtin_amdgcn_mfma_f32_16x16x32_bf16(pf, bf, acc[t], 0,0,0);
            }
        }
        __syncthreads();
        abcur = abnext;
    }

    rs += __shfl_xor(rs, 16);
    rs += __shfl_xor(rs, 32);
    int h = bh & 3;
    #pragma unroll
    for (int j=0;j<4;++j){
        float rsj = __shfl(rs, kq*4 + j);
        float inv = 1.0f / fmaxf(rsj, 1e-30f);
        int n = qb + w*16 + kq*4 + j;
        float* op = out + ((size_t)(b*1024 + n))*256 + h*64 + r16;
        #pragma unroll
        for (int t=0;t<4;++t)
            op[t*16] = acc[t][j] * inv;
    }
}

extern "C" void kernel_launch(void* const* d_in, const int* in_sizes, int n_in,
                              void* d_out, int out_size, void* d_ws, size_t ws_size,
                              hipStream_t stream){
    const float* x   = (const float*)d_in[0];
    const float* adj = (const float*)d_in[1];
    const float* W   = (const float*)d_in[2];
    const float* a   = (const float*)d_in[3];
    float* out = (float*)d_out;
    char* ws = (char*)d_ws;
    // ws: Wt 128KB | hT 4MB | eiL 128KB | ejL 128KB | abits 1MB
    unsigned short* Wt = (unsigned short*)ws;
    unsigned short* hT = (unsigned short*)(ws + (128<<10));
    float* eiL = (float*)(ws + (128<<10) + (4<<20));
    float* ejL = eiL + 32768;
    unsigned long long* abits = (unsigned long long*)(ws + (128<<10) + (4<<20) + (256<<10));

    k_prep <<<2304, 256, 0, stream>>>(adj, abits, W, Wt);
    k_gemm <<<512,  256, 0, stream>>>(x, Wt, a, hT, eiL, ejL);
    k_attn <<<512,  256, 0, stream>>>((const uint2*)abits, hT, eiL, ejL, out);
}